// Round 4
// baseline (271.261 us; speedup 1.0000x reference)
//
#include <hip/hip_runtime.h>
#include <hip/hip_bf16.h>
#include <math.h>

#define Bsz 2
#define Ssz 2048
#define Esz 1024
#define Hsz 16
#define DHsz 64

typedef __bf16 bf16_t;
typedef __attribute__((ext_vector_type(8))) __bf16 bf16x8;
typedef __attribute__((ext_vector_type(4))) float f32x4;

typedef unsigned int u32;
typedef const __attribute__((address_space(1))) u32* gptr_t;
typedef __attribute__((address_space(3))) u32* lptr_t;

#if __has_builtin(__builtin_amdgcn_exp2f)
#define EXP2F(x) __builtin_amdgcn_exp2f(x)
#else
#define EXP2F(x) __expf((x)*0.69314718f)
#endif

__device__ __forceinline__ bf16_t to_bf16(float f) {
  union { float f; unsigned u; } v; v.f = f;
  unsigned r = (v.u + 0x7FFF + ((v.u >> 16) & 1)) >> 16;   // RNE
  union { unsigned short s; bf16_t b; } o; o.s = (unsigned short)r;
  return o.b;
}

// pack two floats to bf16x2 (RTZ) in ONE v_perm_b32
__device__ __forceinline__ unsigned pack2_rtz(float a, float b) {
#if __has_builtin(__builtin_amdgcn_perm)
  return __builtin_amdgcn_perm(__float_as_uint(b), __float_as_uint(a), 0x07060302u);
#else
  return (__float_as_uint(a) >> 16) | (__float_as_uint(b) & 0xFFFF0000u);
#endif
}

__device__ __forceinline__ unsigned pack2(float a, float b) {
  union { float f; unsigned u; } x, y; x.f = a; y.f = b;
  unsigned ra = (x.u + 0x7FFF + ((x.u >> 16) & 1)) >> 16;
  unsigned rb = (y.u + 0x7FFF + ((y.u >> 16) & 1)) >> 16;
  return ra | (rb << 16);
}

__device__ __forceinline__ f32x4 mfma16(bf16x8 a, bf16x8 b, f32x4 c) {
  return __builtin_amdgcn_mfma_f32_16x16x32_bf16(a, b, c, 0, 0, 0);
}

// async global->LDS, 16B per lane; lds base must be wave-uniform
__device__ __forceinline__ void gload16(void* lds, const void* g) {
  __builtin_amdgcn_global_load_lds((gptr_t)g, (lptr_t)lds, 16, 0, 0);
}

// ---------------- fused prep kernel ----------------
// blocks [0,4096): cast x -> bf16 (float4 granularity)
// blocks [4096,4112): mask -> bf16 0/1
// blocks [4112,5136): weight transposes (et 16 x h 16 x z 4)
#define PREP_CAST 4096
#define PREP_MASK 4112
__global__ __launch_bounds__(256) void prep(
    const float* __restrict__ x, const int* __restrict__ mask,
    const float* __restrict__ wq, const float* __restrict__ wk,
    const float* __restrict__ wv, const float* __restrict__ wo,
    bf16_t* __restrict__ xb, bf16_t* __restrict__ mb,
    bf16_t* __restrict__ wAll, bf16_t* __restrict__ wAllV, bf16_t* __restrict__ woT) {
  __shared__ bf16_t lT[64 * 72];
  const int bid = blockIdx.x, t = threadIdx.x;
  if (bid < PREP_CAST) {
    const int i = bid * 256 + t;
    float4 v = ((const float4*)x)[i];
    uint2 o; o.x = pack2(v.x, v.y); o.y = pack2(v.z, v.w);
    ((uint2*)xb)[i] = o;
  } else if (bid < PREP_MASK) {
    const int i = (bid - PREP_CAST) * 256 + t;
    mb[i] = to_bf16(mask[i] ? 1.0f : 0.0f);
  } else {
    const int t2 = bid - PREP_MASK;
    const int et = t2 & 15, h = (t2 >> 4) & 15, z = t2 >> 8;
    const float* src; int srcLD; bf16_t* dst;
    if (z == 0)      { src = wq + ((size_t)h * Esz + et * 64) * DHsz; srcLD = DHsz; dst = wAll  + (size_t)(h * 64) * Esz; }
    else if (z == 1) { src = wk + ((size_t)h * Esz + et * 64) * DHsz; srcLD = DHsz; dst = wAll  + (size_t)(1024 + h * 64) * Esz; }
    else if (z == 2) { src = wv + ((size_t)h * Esz + et * 64) * DHsz; srcLD = DHsz; dst = wAllV + (size_t)(h * 64) * Esz; }
    else             { src = wo + (size_t)(et * 64) * Esz + h * 64;   srcLD = Esz;  dst = woT   + (size_t)(h * 64) * Esz; }
#pragma unroll
    for (int rr = 0; rr < 4; rr++) {
      int er = rr * 16 + (t >> 4);
      int dc = (t & 15) * 4;
      float4 v = *(const float4*)&src[(size_t)er * srcLD + dc];
      lT[(dc + 0) * 72 + er] = to_bf16(v.x);
      lT[(dc + 1) * 72 + er] = to_bf16(v.y);
      lT[(dc + 2) * 72 + er] = to_bf16(v.z);
      lT[(dc + 3) * 72 + er] = to_bf16(v.w);
    }
    __syncthreads();
#pragma unroll
    for (int rr = 0; rr < 2; rr++) {
      int d = rr * 32 + (t >> 3);
      int e8 = (t & 7) * 8;
      bf16x8 o = *(const bf16x8*)&lT[d * 72 + e8];
      *(bf16x8*)&dst[(size_t)d * Esz + et * 64 + e8] = o;
    }
  }
}

// ---------------- generic m97-style GEMM core ----------------
// C[TM x TN] += A[TM x K] . B[TN x K]^T, both row-major (K contiguous).
template <int TM, int TN>
__device__ __forceinline__ void gemm_core(
    const bf16_t* __restrict__ Ab, const bf16_t* __restrict__ Bb, int K,
    bf16_t* lA, bf16_t* lB, f32x4 (&acc)[TM / 32][TN / 32]) {
  const int tid = threadIdx.x, lane = tid & 63, wvi = tid >> 6;
  const int g = lane >> 4, c = lane & 15, cw = c & 7;
  const int lrow = lane >> 3, sg = lane & 7;
  const int wm = wvi >> 1, wn = wvi & 1;
  for (int kc = 0; kc < K; kc += 64) {
#pragma unroll
    for (int j = 0; j < TM / 32; j++) {
      const int base = (j * 4 + wvi) * 8;
      const int row = base + lrow;
      gload16(lA + base * 64, Ab + (size_t)row * K + kc + ((sg ^ (row & 7)) * 8));
    }
#pragma unroll
    for (int j = 0; j < TN / 32; j++) {
      const int base = (j * 4 + wvi) * 8;
      const int row = base + lrow;
      gload16(lB + base * 64, Bb + (size_t)row * K + kc + ((sg ^ (row & 7)) * 8));
    }
    __syncthreads();
#pragma unroll
    for (int ksp = 0; ksp < 2; ksp++) {
      const int kg = (ksp * 4 + g) ^ cw;
      bf16x8 af[TM / 32], bfr[TN / 32];
#pragma unroll
      for (int mt = 0; mt < TM / 32; mt++)
        af[mt] = *(const bf16x8*)&lA[(wm * (TM / 2) + mt * 16 + c) * 64 + kg * 8];
#pragma unroll
      for (int nt = 0; nt < TN / 32; nt++)
        bfr[nt] = *(const bf16x8*)&lB[(wn * (TN / 2) + nt * 16 + c) * 64 + kg * 8];
#pragma unroll
      for (int mt = 0; mt < TM / 32; mt++)
#pragma unroll
        for (int nt = 0; nt < TN / 32; nt++)
          acc[mt][nt] = mfma16(af[mt], bfr[nt], acc[mt][nt]);
    }
    __syncthreads();
  }
}

// ---------------- fused QKV projection ----------------
// blocks [0,512): Q,K GEMM  C = xb[4096x1024].wAll[2048x1024]^T
// blocks [512,1536): V^T GEMM  C = wAllV[1024x1024].xb_b[2048x1024]^T (mask folded)
__global__ __launch_bounds__(256, 2) void qkv_gemm(
    const bf16_t* __restrict__ xb, const bf16_t* __restrict__ wAll,
    const bf16_t* __restrict__ wAllV, const bf16_t* __restrict__ mb,
    const float* __restrict__ bq, const float* __restrict__ bk,
    const float* __restrict__ bv,
    bf16_t* __restrict__ qb, bf16_t* __restrict__ kb, bf16_t* __restrict__ vTb) {
  __shared__ alignas(16) bf16_t lA[128 * 64];
  __shared__ alignas(16) bf16_t lB[128 * 64];
  const int bid = blockIdx.x;
  const int lane = threadIdx.x & 63, wvi = threadIdx.x >> 6;
  const int g = lane >> 4, c = lane & 15;
  const int wm = wvi >> 1, wn = wvi & 1;
  if (bid < 512) {
    f32x4 acc[4][4] = {};
    const int Mb = (bid & 31) * 128, Nb = (bid >> 5) * 128;
    gemm_core<128, 128>(xb + (size_t)Mb * Esz, wAll + (size_t)Nb * Esz, Esz, lA, lB, acc);
#pragma unroll
    for (int nt = 0; nt < 4; nt++) {
      const int col = Nb + wn * 64 + nt * 16 + c;
      const int which = col >> 10, h = (col >> 6) & 15, d = col & 63;
      const float bias = (which ? bk : bq)[h * DHsz + d];
      const float scale = which ? 1.0f : 0.18033688011112042f;  // 0.125*log2(e)
      bf16_t* dst = which ? kb : qb;
#pragma unroll
      for (int mt = 0; mt < 4; mt++)
#pragma unroll
        for (int r = 0; r < 4; r++) {
          const int row = Mb + wm * 64 + mt * 16 + g * 4 + r;
          const int b = row >> 11, s = row & 2047;
          dst[(((size_t)(b * Hsz + h)) * Ssz + s) * DHsz + d] =
              to_bf16((acc[mt][nt][r] + bias) * scale);
        }
    }
  } else {
    const int t2 = bid - 512;
    f32x4 acc[2][4] = {};
    const int Mb = (t2 & 15) * 64, Nb = ((t2 >> 4) & 15) * 128, b = t2 >> 8;
    gemm_core<64, 128>(wAllV + (size_t)Mb * Esz, xb + ((size_t)(b * Ssz) + Nb) * Esz,
                       Esz, lA, lB, acc);
#pragma unroll
    for (int nt = 0; nt < 4; nt++) {
      const int s = Nb + wn * 64 + nt * 16 + c;
      const float mval = (float)mb[b * Ssz + s];   // zero masked V columns
#pragma unroll
      for (int mt = 0; mt < 2; mt++)
#pragma unroll
        for (int r = 0; r < 4; r++) {
          const int m = Mb + wm * 32 + mt * 16 + g * 4 + r;   // = h*64+d
          const size_t obase = ((size_t)(b * Hsz * DHsz + m)) * Ssz;
          vTb[obase + s] = to_bf16((acc[mt][nt][r] + bv[m]) * mval);
        }
    }
  }
}

// ---------------- flash attention: barrier-free, direct-global K/V ----------------
// grid (H, S/128, B), 256 threads. Per wave: 32 q, 64 keys/iter.
// lP per-wave (C->A layout transform). l via MFMA with mask as B-operand.
__global__ __launch_bounds__(256, 2) void flash_attn(
    const bf16_t* __restrict__ qb, const bf16_t* __restrict__ kb,
    const bf16_t* __restrict__ vTb, const bf16_t* __restrict__ mb,
    bf16_t* __restrict__ Ob) {
  __shared__ alignas(16) bf16_t lP[4][32 * 64];

  const int h = blockIdx.x, qt = blockIdx.y, b = blockIdx.z;  // h fastest -> XCD affinity
  const size_t bh = (size_t)(b * Hsz + h);
  const int tid = threadIdx.x, lane = tid & 63, wv = tid >> 6;
  const int g = lane >> 4, c = lane & 15, cw = c & 7;

  const bf16_t* Kbase = kb + bh * (size_t)Ssz * DHsz + c * DHsz + g * 8;
  const bf16_t* Vbase = vTb + bh * (size_t)DHsz * Ssz + c * Ssz + g * 8;
  const bf16_t* mbb = mb + b * Ssz + g * 8;

  // Q fragments (B-operand), loaded once
  bf16x8 qf[2][2];
  const bf16_t* Qbase = qb + (bh * Ssz + qt * 128 + wv * 32) * DHsz;
#pragma unroll
  for (int qsub = 0; qsub < 2; qsub++)
#pragma unroll
    for (int ksp = 0; ksp < 2; ksp++)
      qf[qsub][ksp] = *(const bf16x8*)&Qbase[(qsub * 16 + c) * DHsz + ksp * 32 + g * 8];

  f32x4 o[2][4] = {};
  f32x4 lac[2] = {};

  auto loadK = [&](int tc, bf16x8 (&kf)[2][4]) {
    const bf16_t* kp = Kbase + (size_t)tc * 64 * DHsz;
#pragma unroll
    for (int ksp = 0; ksp < 2; ksp++)
#pragma unroll
      for (int nt = 0; nt < 4; nt++)
        kf[ksp][nt] = *(const bf16x8*)&kp[nt * 16 * DHsz + ksp * 32];
  };

  auto body = [&](int tc, bf16x8 (&kcur)[2][4], bf16x8 (&knext)[2][4]) {
    // V + mask fragments for this iter (used ~after S-MFMA + exp)
    bf16x8 vf[2][4], mfr[2];
    const bf16_t* vp = Vbase + tc * 64;
#pragma unroll
    for (int ksp = 0; ksp < 2; ksp++) {
      mfr[ksp] = *(const bf16x8*)&mbb[tc * 64 + ksp * 32];
#pragma unroll
      for (int dt = 0; dt < 4; dt++)
        vf[ksp][dt] = *(const bf16x8*)&vp[dt * 16 * Ssz + ksp * 32];
    }
    // prefetch next K tile
    if (tc + 1 < 32) loadK(tc + 1, knext);
    // S^T = K . Q^T   (rows = keys, cols = q)
    f32x4 st[2][4] = {};
#pragma unroll
    for (int ksp = 0; ksp < 2; ksp++)
#pragma unroll
      for (int nt = 0; nt < 4; nt++) {
        st[0][nt] = mfma16(kcur[ksp][nt], qf[0][ksp], st[0][nt]);
        st[1][nt] = mfma16(kcur[ksp][nt], qf[1][ksp], st[1][nt]);
      }
    // exp2 + pack (RTZ, 1 perm per pair) -> per-wave lP
#pragma unroll
    for (int qsub = 0; qsub < 2; qsub++)
#pragma unroll
      for (int nt = 0; nt < 4; nt++) {
        float p0 = EXP2F(st[qsub][nt][0]);
        float p1 = EXP2F(st[qsub][nt][1]);
        float p2 = EXP2F(st[qsub][nt][2]);
        float p3 = EXP2F(st[qsub][nt][3]);
        const int pg = (nt * 2 + (g >> 1)) ^ cw;
        uint2 pv; pv.x = pack2_rtz(p0, p1); pv.y = pack2_rtz(p2, p3);
        *(uint2*)&lP[wv][(qsub * 16 + c) * 64 + pg * 8 + (g & 1) * 4] = pv;
      }
    // PV + l (l via MFMA with mask vector as B; V pre-masked in qkv_gemm)
#pragma unroll
    for (int ksp = 0; ksp < 2; ksp++) {
      const int kgr = (ksp * 4 + g) ^ cw;
      bf16x8 pf0 = *(const bf16x8*)&lP[wv][(0 * 16 + c) * 64 + kgr * 8];
      bf16x8 pf1 = *(const bf16x8*)&lP[wv][(1 * 16 + c) * 64 + kgr * 8];
      lac[0] = mfma16(pf0, mfr[ksp], lac[0]);
      lac[1] = mfma16(pf1, mfr[ksp], lac[1]);
#pragma unroll
      for (int dt = 0; dt < 4; dt++) {
        o[0][dt] = mfma16(pf0, vf[ksp][dt], o[0][dt]);
        o[1][dt] = mfma16(pf1, vf[ksp][dt], o[1][dt]);
      }
    }
  };

  bf16x8 kA[2][4], kB[2][4];
  loadK(0, kA);
  for (int tc = 0; tc < 32; tc += 2) {
    body(tc, kA, kB);
    body(tc + 1, kB, kA);
  }

  // epilogue: O row = qsub*16 + g*4 + r (same mapping as lac rows), col = dt*16 + c
#pragma unroll
  for (int qsub = 0; qsub < 2; qsub++)
#pragma unroll
    for (int r = 0; r < 4; r++) {
      const int row = qsub * 16 + g * 4 + r;
      const float linv = 1.0f / fmaxf(lac[qsub][r], 1e-30f);
      const size_t orow = (size_t)(b * Ssz + qt * 128 + wv * 32 + row) * Esz + h * DHsz;
#pragma unroll
      for (int dt = 0; dt < 4; dt++)
        Ob[orow + dt * 16 + c] = to_bf16(o[qsub][dt][r] * linv);
    }
}

// ---------------- output projection ----------------
// C = Ob[4096 x 1024] . woT[1024 x 1024]^T + bo, fp32 out. Tiles 128x64.
__global__ __launch_bounds__(256, 2) void out_gemm(
    const bf16_t* __restrict__ Ob, const bf16_t* __restrict__ woT,
    const float* __restrict__ bo, float* __restrict__ out) {
  __shared__ alignas(16) bf16_t lA[128 * 64];
  __shared__ alignas(16) bf16_t lB[64 * 64];
  f32x4 acc[4][2] = {};
  const int Mb = blockIdx.x * 128, Nb = blockIdx.y * 64;
  gemm_core<128, 64>(Ob + (size_t)Mb * Esz, woT + (size_t)Nb * Esz, Esz, lA, lB, acc);
  const int lane = threadIdx.x & 63, wvi = threadIdx.x >> 6;
  const int g = lane >> 4, c = lane & 15;
  const int wm = wvi >> 1, wn = wvi & 1;
#pragma unroll
  for (int nt = 0; nt < 2; nt++) {
    const int col = Nb + wn * 32 + nt * 16 + c;
    const float bias = bo[col];
#pragma unroll
    for (int mt = 0; mt < 4; mt++)
#pragma unroll
      for (int r = 0; r < 4; r++) {
        const int row = Mb + wm * 64 + mt * 16 + g * 4 + r;
        out[(size_t)row * Esz + col] = acc[mt][nt][r] + bias;
      }
  }
}

extern "C" void kernel_launch(void* const* d_in, const int* in_sizes, int n_in,
                              void* d_out, int out_size, void* d_ws, size_t ws_size,
                              hipStream_t stream) {
  const float* x = (const float*)d_in[0];
  const int* mask = (const int*)d_in[1];
  const float* wq = (const float*)d_in[2];
  const float* bq = (const float*)d_in[3];
  const float* wk = (const float*)d_in[4];
  const float* bk = (const float*)d_in[5];
  const float* wv = (const float*)d_in[6];
  const float* bv = (const float*)d_in[7];
  const float* wo = (const float*)d_in[8];
  const float* bo = (const float*)d_in[9];
  float* out = (float*)d_out;

  char* ws = (char*)d_ws;
  size_t off = 0;
  auto take = [&](size_t bytes) -> char* {
    char* p = ws + off;
    off += (bytes + 255) & ~(size_t)255;
    return p;
  };
  bf16_t* xb    = (bf16_t*)take((size_t)Bsz * Ssz * Esz * 2);
  bf16_t* wAll  = (bf16_t*)take((size_t)2 * Esz * Esz * 2);
  bf16_t* wAllV = (bf16_t*)take((size_t)Esz * Esz * 2);
  bf16_t* woT   = (bf16_t*)take((size_t)Esz * Esz * 2);
  bf16_t* qb    = (bf16_t*)take((size_t)Bsz * Hsz * Ssz * DHsz * 2);
  bf16_t* kb    = (bf16_t*)take((size_t)Bsz * Hsz * Ssz * DHsz * 2);
  bf16_t* vTb   = (bf16_t*)take((size_t)Bsz * Hsz * Ssz * DHsz * 2);
  bf16_t* Ob    = (bf16_t*)take((size_t)Bsz * Ssz * Esz * 2);
  bf16_t* mb    = (bf16_t*)take((size_t)Bsz * Ssz * 2);

  prep<<<5136, 256, 0, stream>>>(x, mask, wq, wk, wv, wo, xb, mb, wAll, wAllV, woT);
  qkv_gemm<<<1536, 256, 0, stream>>>(xb, wAll, wAllV, mb, bq, bk, bv, qb, kb, vTb);
  flash_attn<<<dim3(Hsz, Ssz / 128, Bsz), 256, 0, stream>>>(qb, kb, vTb, mb, Ob);
  out_gemm<<<dim3(Bsz * Ssz / 128, Esz / 64), 256, 0, stream>>>(Ob, woT, bo, out);
}

// Round 5
// 211.226 us; speedup vs baseline: 1.2842x; 1.2842x over previous
//
#include <hip/hip_runtime.h>
#include <hip/hip_bf16.h>
#include <math.h>

#define Bsz 2
#define Ssz 2048
#define Esz 1024
#define Hsz 16
#define DHsz 64

typedef __bf16 bf16_t;
typedef __attribute__((ext_vector_type(8))) __bf16 bf16x8;
typedef __attribute__((ext_vector_type(4))) float f32x4;

typedef unsigned int u32;
typedef const __attribute__((address_space(1))) u32* gptr_t;
typedef __attribute__((address_space(3))) u32* lptr_t;

#if __has_builtin(__builtin_amdgcn_exp2f)
#define EXP2F(x) __builtin_amdgcn_exp2f(x)
#else
#define EXP2F(x) __expf((x)*0.69314718f)
#endif

__device__ __forceinline__ bf16_t to_bf16(float f) {
  union { float f; unsigned u; } v; v.f = f;
  unsigned r = (v.u + 0x7FFF + ((v.u >> 16) & 1)) >> 16;   // RNE
  union { unsigned short s; bf16_t b; } o; o.s = (unsigned short)r;
  return o.b;
}

// pack two floats to bf16x2 (RTZ) in ONE v_perm_b32 (consistent P in num+denom)
__device__ __forceinline__ unsigned pack2_rtz(float a, float b) {
#if __has_builtin(__builtin_amdgcn_perm)
  return __builtin_amdgcn_perm(__float_as_uint(b), __float_as_uint(a), 0x07060302u);
#else
  return (__float_as_uint(a) >> 16) | (__float_as_uint(b) & 0xFFFF0000u);
#endif
}

__device__ __forceinline__ unsigned pack2(float a, float b) {
  union { float f; unsigned u; } x, y; x.f = a; y.f = b;
  unsigned ra = (x.u + 0x7FFF + ((x.u >> 16) & 1)) >> 16;
  unsigned rb = (y.u + 0x7FFF + ((y.u >> 16) & 1)) >> 16;
  return ra | (rb << 16);
}

__device__ __forceinline__ f32x4 mfma16(bf16x8 a, bf16x8 b, f32x4 c) {
  return __builtin_amdgcn_mfma_f32_16x16x32_bf16(a, b, c, 0, 0, 0);
}

// async global->LDS, 16B per lane; lds base must be wave-uniform
__device__ __forceinline__ void gload16(void* lds, const void* g) {
  __builtin_amdgcn_global_load_lds((gptr_t)g, (lptr_t)lds, 16, 0, 0);
}

// ---------------- fused prep kernel ----------------
#define PREP_CAST 4096
#define PREP_MASK 4112
__global__ __launch_bounds__(256) void prep(
    const float* __restrict__ x, const int* __restrict__ mask,
    const float* __restrict__ wq, const float* __restrict__ wk,
    const float* __restrict__ wv, const float* __restrict__ wo,
    bf16_t* __restrict__ xb, bf16_t* __restrict__ mb,
    bf16_t* __restrict__ wAll, bf16_t* __restrict__ wAllV, bf16_t* __restrict__ woT) {
  __shared__ bf16_t lT[64 * 72];
  const int bid = blockIdx.x, t = threadIdx.x;
  if (bid < PREP_CAST) {
    const int i = bid * 256 + t;
    float4 v = ((const float4*)x)[i];
    uint2 o; o.x = pack2(v.x, v.y); o.y = pack2(v.z, v.w);
    ((uint2*)xb)[i] = o;
  } else if (bid < PREP_MASK) {
    const int i = (bid - PREP_CAST) * 256 + t;
    mb[i] = to_bf16(mask[i] ? 1.0f : 0.0f);
  } else {
    const int t2 = bid - PREP_MASK;
    const int et = t2 & 15, h = (t2 >> 4) & 15, z = t2 >> 8;
    const float* src; int srcLD; bf16_t* dst;
    if (z == 0)      { src = wq + ((size_t)h * Esz + et * 64) * DHsz; srcLD = DHsz; dst = wAll  + (size_t)(h * 64) * Esz; }
    else if (z == 1) { src = wk + ((size_t)h * Esz + et * 64) * DHsz; srcLD = DHsz; dst = wAll  + (size_t)(1024 + h * 64) * Esz; }
    else if (z == 2) { src = wv + ((size_t)h * Esz + et * 64) * DHsz; srcLD = DHsz; dst = wAllV + (size_t)(h * 64) * Esz; }
    else             { src = wo + (size_t)(et * 64) * Esz + h * 64;   srcLD = Esz;  dst = woT   + (size_t)(h * 64) * Esz; }
#pragma unroll
    for (int rr = 0; rr < 4; rr++) {
      int er = rr * 16 + (t >> 4);
      int dc = (t & 15) * 4;
      float4 v = *(const float4*)&src[(size_t)er * srcLD + dc];
      lT[(dc + 0) * 72 + er] = to_bf16(v.x);
      lT[(dc + 1) * 72 + er] = to_bf16(v.y);
      lT[(dc + 2) * 72 + er] = to_bf16(v.z);
      lT[(dc + 3) * 72 + er] = to_bf16(v.w);
    }
    __syncthreads();
#pragma unroll
    for (int rr = 0; rr < 2; rr++) {
      int d = rr * 32 + (t >> 3);
      int e8 = (t & 7) * 8;
      bf16x8 o = *(const bf16x8*)&lT[d * 72 + e8];
      *(bf16x8*)&dst[(size_t)d * Esz + et * 64 + e8] = o;
    }
  }
}

// ---------------- generic m97-style GEMM core (256 threads) ----------------
template <int TM, int TN>
__device__ __forceinline__ void gemm_core(
    const bf16_t* __restrict__ Ab, const bf16_t* __restrict__ Bb, int K,
    bf16_t* lA, bf16_t* lB, f32x4 (&acc)[TM / 32][TN / 32]) {
  const int tid = threadIdx.x, lane = tid & 63, wvi = tid >> 6;
  const int g = lane >> 4, c = lane & 15, cw = c & 7;
  const int lrow = lane >> 3, sg = lane & 7;
  const int wm = wvi >> 1, wn = wvi & 1;
  for (int kc = 0; kc < K; kc += 64) {
#pragma unroll
    for (int j = 0; j < TM / 32; j++) {
      const int base = (j * 4 + wvi) * 8;
      const int row = base + lrow;
      gload16(lA + base * 64, Ab + (size_t)row * K + kc + ((sg ^ (row & 7)) * 8));
    }
#pragma unroll
    for (int j = 0; j < TN / 32; j++) {
      const int base = (j * 4 + wvi) * 8;
      const int row = base + lrow;
      gload16(lB + base * 64, Bb + (size_t)row * K + kc + ((sg ^ (row & 7)) * 8));
    }
    __syncthreads();
#pragma unroll
    for (int ksp = 0; ksp < 2; ksp++) {
      const int kg = (ksp * 4 + g) ^ cw;
      bf16x8 af[TM / 32], bfr[TN / 32];
#pragma unroll
      for (int mt = 0; mt < TM / 32; mt++)
        af[mt] = *(const bf16x8*)&lA[(wm * (TM / 2) + mt * 16 + c) * 64 + kg * 8];
#pragma unroll
      for (int nt = 0; nt < TN / 32; nt++)
        bfr[nt] = *(const bf16x8*)&lB[(wn * (TN / 2) + nt * 16 + c) * 64 + kg * 8];
#pragma unroll
      for (int mt = 0; mt < TM / 32; mt++)
#pragma unroll
        for (int nt = 0; nt < TN / 32; nt++)
          acc[mt][nt] = mfma16(af[mt], bfr[nt], acc[mt][nt]);
    }
    __syncthreads();
  }
}

// ---------------- fused QKV projection (all 128x128 tiles) ----------------
// blocks [0,512): Q,K GEMM  C = xb[4096x1024].wAll[2048x1024]^T
// blocks [512,768): V^T GEMM  C = wAllV[1024x1024].xb_b[2048x1024]^T (mask folded)
__global__ __launch_bounds__(256, 3) void qkv_gemm(
    const bf16_t* __restrict__ xb, const bf16_t* __restrict__ wAll,
    const bf16_t* __restrict__ wAllV, const bf16_t* __restrict__ mb,
    const float* __restrict__ bq, const float* __restrict__ bk,
    const float* __restrict__ bv,
    bf16_t* __restrict__ qb, bf16_t* __restrict__ kb, bf16_t* __restrict__ vTb) {
  __shared__ alignas(16) bf16_t lA[128 * 64];
  __shared__ alignas(16) bf16_t lB[128 * 64];
  const int bid = blockIdx.x;
  const int lane = threadIdx.x & 63, wvi = threadIdx.x >> 6;
  const int g = lane >> 4, c = lane & 15;
  const int wm = wvi >> 1, wn = wvi & 1;
  f32x4 acc[4][4] = {};
  if (bid < 512) {
    const int Mb = (bid & 31) * 128, Nb = (bid >> 5) * 128;
    gemm_core<128, 128>(xb + (size_t)Mb * Esz, wAll + (size_t)Nb * Esz, Esz, lA, lB, acc);
#pragma unroll
    for (int nt = 0; nt < 4; nt++) {
      const int col = Nb + wn * 64 + nt * 16 + c;
      const int which = col >> 10, h = (col >> 6) & 15, d = col & 63;
      const float bias = (which ? bk : bq)[h * DHsz + d];
      const float scale = which ? 1.0f : 0.18033688011112042f;  // 0.125*log2(e)
      bf16_t* dst = which ? kb : qb;
#pragma unroll
      for (int mt = 0; mt < 4; mt++)
#pragma unroll
        for (int r = 0; r < 4; r++) {
          const int row = Mb + wm * 64 + mt * 16 + g * 4 + r;
          const int b = row >> 11, s = row & 2047;
          dst[(((size_t)(b * Hsz + h)) * Ssz + s) * DHsz + d] =
              to_bf16((acc[mt][nt][r] + bias) * scale);
        }
    }
  } else {
    const int t2 = bid - 512;
    const int Mb = (t2 & 7) * 128, Nb = ((t2 >> 3) & 15) * 128, b = t2 >> 7;
    gemm_core<128, 128>(wAllV + (size_t)Mb * Esz, xb + ((size_t)(b * Ssz) + Nb) * Esz,
                        Esz, lA, lB, acc);
#pragma unroll
    for (int nt = 0; nt < 4; nt++) {
      const int s = Nb + wn * 64 + nt * 16 + c;
      const float mval = (float)mb[b * Ssz + s];   // zero masked V columns
#pragma unroll
      for (int mt = 0; mt < 4; mt++)
#pragma unroll
        for (int r = 0; r < 4; r++) {
          const int m = Mb + wm * 64 + mt * 16 + g * 4 + r;   // = h*64+d
          vTb[((size_t)(b * 1024 + m)) * Ssz + s] = to_bf16((acc[mt][nt][r] + bv[m]) * mval);
        }
    }
  }
}

// ---------------- flash attention: K LDS-staged (DMA dbuf), V reg-prefetched ----
// grid (H, S/64, B), 128 threads (2 waves), 32 q/wave, 64 keys/iter.
__global__ __launch_bounds__(128, 2) void flash_attn(
    const bf16_t* __restrict__ qb, const bf16_t* __restrict__ kb,
    const bf16_t* __restrict__ vTb, const bf16_t* __restrict__ mb,
    bf16_t* __restrict__ Ob) {
  __shared__ alignas(16) bf16_t lK[2][64 * 64];
  __shared__ alignas(16) bf16_t lP[2][32 * 64];

  const int h = blockIdx.x, qt = blockIdx.y, b = blockIdx.z;  // h fastest -> XCD affinity
  const size_t bh = (size_t)(b * Hsz + h);
  const int tid = threadIdx.x, lane = tid & 63, wv = tid >> 6;  // wv in {0,1}
  const int g = lane >> 4, c = lane & 15, cw = c & 7;
  const int lrow = lane >> 3, sg = lane & 7;

  const bf16_t* Kbase = kb + bh * (size_t)Ssz * DHsz;
  const bf16_t* Vlane = vTb + bh * (size_t)DHsz * Ssz + c * Ssz + g * 8;
  const bf16_t* mbb = mb + b * Ssz + g * 8;

  // Q fragments (B-operand), loaded once
  bf16x8 qf[2][2];
  const bf16_t* Qbase = qb + (bh * Ssz + qt * 64 + wv * 32) * DHsz;
#pragma unroll
  for (int qsub = 0; qsub < 2; qsub++)
#pragma unroll
    for (int ksp = 0; ksp < 2; ksp++)
      qf[qsub][ksp] = *(const bf16x8*)&Qbase[(qsub * 16 + c) * DHsz + ksp * 32 + g * 8];

  f32x4 o[2][4] = {};
  f32x4 lac[2] = {};

  // stage K tile (64x64) for key-chunk tc into lK[buf]; swizzled granules
  auto stage = [&](int tc, int buf) {
#pragma unroll
    for (int j = 0; j < 4; j++) {
      const int rowbase = wv * 32 + j * 8;
      const int row = rowbase + lrow;
      const int lg = sg ^ (row & 7);
      gload16(&lK[buf][rowbase * 64], Kbase + ((size_t)(tc * 64 + row)) * DHsz + lg * 8);
    }
  };

  auto loadVM = [&](int tc, bf16x8 (&vf)[2][4], bf16x8 (&mfr)[2]) {
    const bf16_t* vp = Vlane + tc * 64;
#pragma unroll
    for (int ksp = 0; ksp < 2; ksp++) {
      mfr[ksp] = *(const bf16x8*)&mbb[tc * 64 + ksp * 32];
#pragma unroll
      for (int dt = 0; dt < 4; dt++)
        vf[ksp][dt] = *(const bf16x8*)&vp[dt * 16 * Ssz + ksp * 32];
    }
  };

  auto compute = [&](int buf, bf16x8 (&vf)[2][4], bf16x8 (&mfr)[2]) {
    const bf16_t* Kt = lK[buf];
    f32x4 st[2][4] = {};
#pragma unroll
    for (int ksp = 0; ksp < 2; ksp++) {
      const int kgr = (ksp * 4 + g) ^ cw;
#pragma unroll
      for (int nt = 0; nt < 4; nt++) {
        bf16x8 kf = *(const bf16x8*)&Kt[(nt * 16 + c) * 64 + kgr * 8];
        st[0][nt] = mfma16(kf, qf[0][ksp], st[0][nt]);
        st[1][nt] = mfma16(kf, qf[1][ksp], st[1][nt]);
      }
    }
    // exp2 + RTZ pack -> per-wave lP (C-layout -> A-layout round trip)
#pragma unroll
    for (int qsub = 0; qsub < 2; qsub++)
#pragma unroll
      for (int nt = 0; nt < 4; nt++) {
        float p0 = EXP2F(st[qsub][nt][0]);
        float p1 = EXP2F(st[qsub][nt][1]);
        float p2 = EXP2F(st[qsub][nt][2]);
        float p3 = EXP2F(st[qsub][nt][3]);
        const int pg = (nt * 2 + (g >> 1)) ^ cw;
        uint2 pv; pv.x = pack2_rtz(p0, p1); pv.y = pack2_rtz(p2, p3);
        *(uint2*)&lP[wv][(qsub * 16 + c) * 64 + pg * 8 + (g & 1) * 4] = pv;
      }
    // PV + l (l via MFMA with mask as B; V pre-masked in qkv_gemm)
#pragma unroll
    for (int ksp = 0; ksp < 2; ksp++) {
      const int kgr = (ksp * 4 + g) ^ cw;
      bf16x8 pf0 = *(const bf16x8*)&lP[wv][(0 * 16 + c) * 64 + kgr * 8];
      bf16x8 pf1 = *(const bf16x8*)&lP[wv][(1 * 16 + c) * 64 + kgr * 8];
      lac[0] = mfma16(pf0, mfr[ksp], lac[0]);
      lac[1] = mfma16(pf1, mfr[ksp], lac[1]);
#pragma unroll
      for (int dt = 0; dt < 4; dt++) {
        o[0][dt] = mfma16(pf0, vf[ksp][dt], o[0][dt]);
        o[1][dt] = mfma16(pf1, vf[ksp][dt], o[1][dt]);
      }
    }
  };

  bf16x8 vA[2][4], vB[2][4], mA[2], mB[2];
  stage(0, 0);
  loadVM(0, vA, mA);
  __syncthreads();
  for (int tc = 0; tc < 32; tc += 2) {
    // stage/prefetch tc+1 while computing tc
    stage(tc + 1, 1);
    loadVM(tc + 1, vB, mB);
    compute(0, vA, mA);
    __syncthreads();
    if (tc + 2 < 32) {
      stage(tc + 2, 0);
      loadVM(tc + 2, vA, mA);
    }
    compute(1, vB, mB);
    __syncthreads();
  }

  // epilogue: O row = qsub*16 + g*4 + r, col = dt*16 + c; l in lac[qsub][r]
#pragma unroll
  for (int qsub = 0; qsub < 2; qsub++)
#pragma unroll
    for (int r = 0; r < 4; r++) {
      const int row = qsub * 16 + g * 4 + r;
      const float linv = 1.0f / fmaxf(lac[qsub][r], 1e-30f);
      const size_t orow = (size_t)(b * Ssz + qt * 64 + wv * 32 + row) * Esz + h * DHsz;
#pragma unroll
      for (int dt = 0; dt < 4; dt++)
        Ob[orow + dt * 16 + c] = to_bf16(o[qsub][dt][r] * linv);
    }
}

// ---------------- output projection ----------------
// C = Ob[4096 x 1024] . woT[1024 x 1024]^T + bo, fp32 out. Tiles 128x64.
__global__ __launch_bounds__(256, 3) void out_gemm(
    const bf16_t* __restrict__ Ob, const bf16_t* __restrict__ woT,
    const float* __restrict__ bo, float* __restrict__ out) {
  __shared__ alignas(16) bf16_t lA[128 * 64];
  __shared__ alignas(16) bf16_t lB[64 * 64];
  f32x4 acc[4][2] = {};
  const int Mb = blockIdx.x * 128, Nb = blockIdx.y * 64;
  gemm_core<128, 64>(Ob + (size_t)Mb * Esz, woT + (size_t)Nb * Esz, Esz, lA, lB, acc);
  const int lane = threadIdx.x & 63, wvi = threadIdx.x >> 6;
  const int g = lane >> 4, c = lane & 15;
  const int wm = wvi >> 1, wn = wvi & 1;
#pragma unroll
  for (int nt = 0; nt < 2; nt++) {
    const int col = Nb + wn * 32 + nt * 16 + c;
    const float bias = bo[col];
#pragma unroll
    for (int mt = 0; mt < 4; mt++)
#pragma unroll
      for (int r = 0; r < 4; r++) {
        const int row = Mb + wm * 64 + mt * 16 + g * 4 + r;
        out[(size_t)row * Esz + col] = acc[mt][nt][r] + bias;
      }
  }
}

extern "C" void kernel_launch(void* const* d_in, const int* in_sizes, int n_in,
                              void* d_out, int out_size, void* d_ws, size_t ws_size,
                              hipStream_t stream) {
  const float* x = (const float*)d_in[0];
  const int* mask = (const int*)d_in[1];
  const float* wq = (const float*)d_in[2];
  const float* bq = (const float*)d_in[3];
  const float* wk = (const float*)d_in[4];
  const float* bk = (const float*)d_in[5];
  const float* wv = (const float*)d_in[6];
  const float* bv = (const float*)d_in[7];
  const float* wo = (const float*)d_in[8];
  const float* bo = (const float*)d_in[9];
  float* out = (float*)d_out;

  char* ws = (char*)d_ws;
  size_t off = 0;
  auto take = [&](size_t bytes) -> char* {
    char* p = ws + off;
    off += (bytes + 255) & ~(size_t)255;
    return p;
  };
  bf16_t* xb    = (bf16_t*)take((size_t)Bsz * Ssz * Esz * 2);
  bf16_t* wAll  = (bf16_t*)take((size_t)2 * Esz * Esz * 2);
  bf16_t* wAllV = (bf16_t*)take((size_t)Esz * Esz * 2);
  bf16_t* woT   = (bf16_t*)take((size_t)Esz * Esz * 2);
  bf16_t* qb    = (bf16_t*)take((size_t)Bsz * Hsz * Ssz * DHsz * 2);
  bf16_t* kb    = (bf16_t*)take((size_t)Bsz * Hsz * Ssz * DHsz * 2);
  bf16_t* vTb   = (bf16_t*)take((size_t)Bsz * Hsz * Ssz * DHsz * 2);
  bf16_t* Ob    = (bf16_t*)take((size_t)Bsz * Ssz * Esz * 2);
  bf16_t* mb    = (bf16_t*)take((size_t)Bsz * Ssz * 2);

  prep<<<5136, 256, 0, stream>>>(x, mask, wq, wk, wv, wo, xb, mb, wAll, wAllV, woT);
  qkv_gemm<<<768, 256, 0, stream>>>(xb, wAll, wAllV, mb, bq, bk, bv, qb, kb, vTb);
  flash_attn<<<dim3(Hsz, Ssz / 64, Bsz), 128, 0, stream>>>(qb, kb, vTb, mb, Ob);
  out_gemm<<<dim3(Bsz * Ssz / 128, Esz / 64), 256, 0, stream>>>(Ob, woT, bo, out);
}